// Round 5
// baseline (99799.463 us; speedup 1.0000x reference)
//
#include <hip/hip_runtime.h>
#include <hip/hip_fp16.h>

static constexpr int kH   = 2048;
static constexpr int kS   = 8192;
static constexpr int kNWG = 256;
static constexpr int kTHR = 576;   // 8 compute waves + 1 poller wave

typedef float        v2f __attribute__((ext_vector_type(2)));
typedef unsigned int v4u __attribute__((ext_vector_type(4)));

__device__ __forceinline__ v2f unpk_bf(unsigned int u) {
    union { unsigned int i; float f; } lo, hi;
    lo.i = u << 16; hi.i = u & 0xffff0000u;
    v2f r; r[0] = lo.f; r[1] = hi.f; return r;
}
__device__ __forceinline__ unsigned int pkbf(float lo, float hi) {
    union { float f; unsigned int u; } a, b; a.f = lo; b.f = hi;
    unsigned int ar = a.u + 0x7fffu + ((a.u >> 16) & 1u);
    unsigned int br = b.u + 0x7fffu + ((b.u >> 16) & 1u);
    return (ar >> 16) | (br & 0xffff0000u);
}
__device__ __forceinline__ v2f cvt2h(unsigned int u) {
    __half2 h = *(__half2*)&u;
    float2 f = __half22float2(h);
    v2f r; r[0] = f.x; r[1] = f.y; return r;
}

// Blocking MALL-coherent sweep of one 8 KB slot: 8 x dwordx4 per lane.
// (global offset imm is 13-bit signed -> two base pointers, offsets <= 3072.)
__device__ __forceinline__ void sweep8(const void* p, const void* p2,
                                       v4u& q0, v4u& q1, v4u& q2, v4u& q3,
                                       v4u& q4, v4u& q5, v4u& q6, v4u& q7) {
    asm volatile("global_load_dwordx4 %0, %8, off sc0 sc1\n\t"
                 "global_load_dwordx4 %1, %8, off offset:1024 sc0 sc1\n\t"
                 "global_load_dwordx4 %2, %8, off offset:2048 sc0 sc1\n\t"
                 "global_load_dwordx4 %3, %8, off offset:3072 sc0 sc1\n\t"
                 "global_load_dwordx4 %4, %9, off sc0 sc1\n\t"
                 "global_load_dwordx4 %5, %9, off offset:1024 sc0 sc1\n\t"
                 "global_load_dwordx4 %6, %9, off offset:2048 sc0 sc1\n\t"
                 "global_load_dwordx4 %7, %9, off offset:3072 sc0 sc1\n\t"
                 "s_waitcnt vmcnt(0)"
                 : "=&v"(q0), "=&v"(q1), "=&v"(q2), "=&v"(q3),
                   "=&v"(q4), "=&v"(q5), "=&v"(q6), "=&v"(q7)
                 : "v"(p), "v"(p2) : "memory");
}
// Single 4B coherent store: f16 payload | (step tag << 16) — atomic dword.
__device__ __forceinline__ void store4_coh(void* p, unsigned int v) {
    asm volatile("global_store_dword %0, %1, off sc0 sc1"
                 :: "v"(p), "v"(v) : "memory");
}

// 6-stage DPP wave64 sum; total lands in lane 63 (proven in round 4).
#define DPP_ADD(v, ctrl)                                                      \
    v += __int_as_float(__builtin_amdgcn_update_dpp(                          \
        0, __float_as_int(v), (ctrl), 0xf, 0xf, true))
#define RED_STAGE(ctrl) do { DPP_ADD(pr, ctrl); DPP_ADD(pz, ctrl);            \
                             DPP_ADD(pxn, ctrl); DPP_ADD(phn, ctrl); } while (0)

// Persistent GRU. 256 WGs x 576 threads (8 compute waves + 1 poller wave).
// Records: 2 slots (by step parity) x 2048 x 4B dword = f16(h_e) | (step<<16).
// Tags are unique per step (8192 < 65536) -> no ABA; skew bound (any poller
// waiting for T implies all tags in {T, T+1}) puts T+1 in the other parity
// slot, so exact-equality detection is safe (same argument as the proven
// toggle protocol).
// Compute wave wv owns e = wg*8+wv; lane l: x-side cols 4l+256m (m<8),
// h-side cols 8l+512m (m<4) — byte-identical to the 18.2ms round-4 kernel.
// Per-step chain: poller sees all tags t -> packs f16 payloads -> hlds ->
// barrier -> compute waves h-proj/reduce/act -> lane63 publishes tag t+1
// (no sync2, no hpub, no pack hop) -> x-proj for t+1 (hidden under wire).
__global__ __launch_bounds__(kTHR)
void gru_persistent(const float* __restrict__ x,    // [S,H] f32
                    const float* __restrict__ Wih,  // [3H,H] f32
                    const float* __restrict__ Whh,  // [3H,H] f32
                    const float* __restrict__ bih,  // [3H] f32
                    const float* __restrict__ bhh,  // [3H] f32
                    float* __restrict__ out,        // [H] f32
                    unsigned char* __restrict__ rec) // 2 slots * 8192 B (zeroed)
{
    __shared__ __align__(16) unsigned short hlds[kH];  // h_t as f16, col c at [c]

    const int wg  = blockIdx.x;
    const int tid = threadIdx.x;
    const int wv  = tid >> 6;      // 0..8
    const int l   = tid & 63;      // 0..63

    if (wv == 8) {
        // ---------------- dedicated poller wave ----------------
        // Lane l, load j covers records j*256 + 4l .. +3.
        const char* b0 = (const char*)rec + l * 16;
        const char* b1 = b0 + 8192;
#pragma unroll 1
        for (int t = 0; t < kS; ++t) {
            const char* base = (t & 1) ? b1 : b0;
            const unsigned int tg = (unsigned int)t << 16;
            v4u q0, q1, q2, q3, q4, q5, q6, q7;
            for (;;) {
                sweep8(base, base + 4096, q0, q1, q2, q3, q4, q5, q6, q7);
                unsigned int a;
                a  = (q0.x^tg)|(q0.y^tg)|(q0.z^tg)|(q0.w^tg);
                a |= (q1.x^tg)|(q1.y^tg)|(q1.z^tg)|(q1.w^tg);
                a |= (q2.x^tg)|(q2.y^tg)|(q2.z^tg)|(q2.w^tg);
                a |= (q3.x^tg)|(q3.y^tg)|(q3.z^tg)|(q3.w^tg);
                a |= (q4.x^tg)|(q4.y^tg)|(q4.z^tg)|(q4.w^tg);
                a |= (q5.x^tg)|(q5.y^tg)|(q5.z^tg)|(q5.w^tg);
                a |= (q6.x^tg)|(q6.y^tg)|(q6.z^tg)|(q6.w^tg);
                a |= (q7.x^tg)|(q7.y^tg)|(q7.z^tg)|(q7.w^tg);
                if (__all((a & 0xffff0000u) == 0u)) break;
            }
            // Pack f16 payloads, broadcast to hlds (layout identical to r4).
            uint2 w;
            w.x = (q0.x & 0xffffu) | (q0.y << 16);
            w.y = (q0.z & 0xffffu) | (q0.w << 16);
            *(uint2*)&hlds[0 * 256 + 4 * l] = w;
            w.x = (q1.x & 0xffffu) | (q1.y << 16);
            w.y = (q1.z & 0xffffu) | (q1.w << 16);
            *(uint2*)&hlds[1 * 256 + 4 * l] = w;
            w.x = (q2.x & 0xffffu) | (q2.y << 16);
            w.y = (q2.z & 0xffffu) | (q2.w << 16);
            *(uint2*)&hlds[2 * 256 + 4 * l] = w;
            w.x = (q3.x & 0xffffu) | (q3.y << 16);
            w.y = (q3.z & 0xffffu) | (q3.w << 16);
            *(uint2*)&hlds[3 * 256 + 4 * l] = w;
            w.x = (q4.x & 0xffffu) | (q4.y << 16);
            w.y = (q4.z & 0xffffu) | (q4.w << 16);
            *(uint2*)&hlds[4 * 256 + 4 * l] = w;
            w.x = (q5.x & 0xffffu) | (q5.y << 16);
            w.y = (q5.z & 0xffffu) | (q5.w << 16);
            *(uint2*)&hlds[5 * 256 + 4 * l] = w;
            w.x = (q6.x & 0xffffu) | (q6.y << 16);
            w.y = (q6.z & 0xffffu) | (q6.w << 16);
            *(uint2*)&hlds[6 * 256 + 4 * l] = w;
            w.x = (q7.x & 0xffffu) | (q7.y << 16);
            w.y = (q7.z & 0xffffu) | (q7.w << 16);
            *(uint2*)&hlds[7 * 256 + 4 * l] = w;
            __syncthreads();   // release compute waves for step t
        }
        return;
    }

    // ---------------- compute waves (round-4 verbatim math) ----------------
    const int e  = wg * 8 + wv;
    const int cb = 4 * l;          // x-side col base
    const int hb = 8 * l;          // h-side col base

    v2f   whh2[3][4][4];
    uint2 wihp[3][8];
#pragma unroll
    for (int G = 0; G < 3; ++G) {
        const size_t row = (size_t)(G * kH + e) * kH;
#pragma unroll
        for (int m = 0; m < 4; ++m) {
            const size_t off = row + hb + 512 * m;
            const float4 w0 = *(const float4*)(Whh + off);
            const float4 w1 = *(const float4*)(Whh + off + 4);
            whh2[G][m][0][0] = w0.x; whh2[G][m][0][1] = w0.y;
            whh2[G][m][1][0] = w0.z; whh2[G][m][1][1] = w0.w;
            whh2[G][m][2][0] = w1.x; whh2[G][m][2][1] = w1.y;
            whh2[G][m][3][0] = w1.z; whh2[G][m][3][1] = w1.w;
        }
#pragma unroll
        for (int m = 0; m < 8; ++m) {
            const float4 iw = *(const float4*)(Wih + row + cb + 256 * m);
            wihp[G][m].x = pkbf(iw.x, iw.y);
            wihp[G][m].y = pkbf(iw.z, iw.w);
        }
    }
    const float bir  = bih[e];
    const float biz  = bih[kH + e];
    const float bin_ = bih[2 * kH + e];
    const float bhr  = bhh[e];
    const float bhz  = bhh[kH + e];
    const float bhn  = bhh[2 * kH + e];

    float hold = 0.0f;  // h for element e (valid on l==63)

    v2f zero2; zero2[0] = 0.f; zero2[1] = 0.f;
    v2f ar = zero2, az = zero2, an = zero2;
    {   // x-proj for step 0 (prologue)
        const float* xrow = x;
#pragma unroll
        for (int m = 0; m < 8; ++m) {
            const float4 xv = *(const float4*)(xrow + cb + 256 * m);
            v2f x0; x0[0] = xv.x; x0[1] = xv.y;
            v2f x1; x1[0] = xv.z; x1[1] = xv.w;
            ar += unpk_bf(wihp[0][m].x) * x0 + unpk_bf(wihp[0][m].y) * x1;
            az += unpk_bf(wihp[1][m].x) * x0 + unpk_bf(wihp[1][m].y) * x1;
            an += unpk_bf(wihp[2][m].x) * x0 + unpk_bf(wihp[2][m].y) * x1;
        }
    }

#pragma unroll 1
    for (int t = 0; t < kS; ++t) {
        __syncthreads();   // poller has broadcast h_t into hlds

        // ---- h projection from LDS f16: 4x ds_read_b128 per lane ----
        v2f hr = zero2, hz = zero2, hn = zero2;
#pragma unroll
        for (int m = 0; m < 4; ++m) {
            const v4u hu = *(const v4u*)&hlds[hb + 512 * m];
            const v2f h0 = cvt2h(hu.x);
            const v2f h1 = cvt2h(hu.y);
            const v2f h2 = cvt2h(hu.z);
            const v2f h3 = cvt2h(hu.w);
            hr += whh2[0][m][0] * h0 + whh2[0][m][1] * h1 +
                  whh2[0][m][2] * h2 + whh2[0][m][3] * h3;
            hz += whh2[1][m][0] * h0 + whh2[1][m][1] * h1 +
                  whh2[1][m][2] * h2 + whh2[1][m][3] * h3;
            hn += whh2[2][m][0] * h0 + whh2[2][m][1] * h1 +
                  whh2[2][m][2] * h2 + whh2[2][m][3] * h3;
        }

        // ---- full-wave DPP reduce; totals land in lane 63 ----
        float pr  = ar[0] + ar[1] + hr[0] + hr[1];
        float pz  = az[0] + az[1] + hz[0] + hz[1];
        float pxn = an[0] + an[1];
        float phn = hn[0] + hn[1];
        RED_STAGE(0xB1);   // quad_perm xor1
        RED_STAGE(0x4E);   // quad_perm xor2
        RED_STAGE(0x141);  // row_half_mirror
        RED_STAGE(0x140);  // row_mirror
        RED_STAGE(0x142);  // row_bcast15
        RED_STAGE(0x143);  // row_bcast31

        if (l == 63) {
            const float r = 1.f / (1.f + __expf(-(pr + bir + bhr)));
            const float z = 1.f / (1.f + __expf(-(pz + biz + bhz)));
            const float a = (pxn + bin_) + r * (phn + bhn);
            const float ee = __expf(-2.f * fabsf(a));
            float th = (1.f - ee) / (1.f + ee);
            th = (a < 0.f) ? -th : th;
            hold = (1.f - z) * th + z * hold;
            const __half hh = __float2half(hold);
            const unsigned int d = (unsigned int)*(const unsigned short*)&hh
                                 | ((unsigned int)(t + 1) << 16);
            // per-wave publish: no sync2, no pack hop — store fires the
            // moment this wave's activation is done.
            store4_coh((char*)rec + ((t + 1) & 1) * 8192 + e * 4, d);
        }

        // ---- x projection for step t+1 (hidden under the wire wait) ----
        {
            const float* xrow = x + (size_t)(t + 1 < kS ? t + 1 : t) * kH;
            ar = zero2; az = zero2; an = zero2;
#pragma unroll
            for (int m = 0; m < 8; ++m) {
                const float4 xv = *(const float4*)(xrow + cb + 256 * m);
                v2f x0; x0[0] = xv.x; x0[1] = xv.y;
                v2f x1; x1[0] = xv.z; x1[1] = xv.w;
                ar += unpk_bf(wihp[0][m].x) * x0 + unpk_bf(wihp[0][m].y) * x1;
                az += unpk_bf(wihp[1][m].x) * x0 + unpk_bf(wihp[1][m].y) * x1;
                an += unpk_bf(wihp[2][m].x) * x0 + unpk_bf(wihp[2][m].y) * x1;
            }
        }
    }

    if (l == 63)
        out[e] = hold;
}

extern "C" void kernel_launch(void* const* d_in, const int* in_sizes, int n_in,
                              void* d_out, int out_size, void* d_ws, size_t ws_size,
                              hipStream_t stream) {
    (void)in_sizes; (void)n_in; (void)out_size; (void)ws_size;
    const float* x   = (const float*)d_in[0];
    const float* Wih = (const float*)d_in[1];
    const float* Whh = (const float*)d_in[2];
    const float* bih = (const float*)d_in[3];
    const float* bhh = (const float*)d_in[4];

    unsigned char* rec = (unsigned char*)d_ws;   // 2 slots * 8192 B
    hipMemsetAsync(rec, 0, 16384, stream);       // h_0 = 0 with tag 0 in slot 0
    gru_persistent<<<dim3(kNWG), dim3(kTHR), 0, stream>>>(
        x, Wih, Whh, bih, bhh, (float*)d_out, rec);
}

// Round 6
// 72207.007 us; speedup vs baseline: 1.3821x; 1.3821x over previous
//
#include <hip/hip_runtime.h>
#include <hip/hip_fp16.h>

static constexpr int kH   = 2048;
static constexpr int kS   = 8192;
static constexpr int kNWG = 256;
static constexpr int kTHR = 576;   // 8 compute waves + 1 poller wave

typedef float        v2f __attribute__((ext_vector_type(2)));
typedef unsigned int v4u __attribute__((ext_vector_type(4)));

__device__ __forceinline__ v2f unpk_bf(unsigned int u) {
    union { unsigned int i; float f; } lo, hi;
    lo.i = u << 16; hi.i = u & 0xffff0000u;
    v2f r; r[0] = lo.f; r[1] = hi.f; return r;
}
__device__ __forceinline__ unsigned int pkbf(float lo, float hi) {
    union { float f; unsigned int u; } a, b; a.f = lo; b.f = hi;
    unsigned int ar = a.u + 0x7fffu + ((a.u >> 16) & 1u);
    unsigned int br = b.u + 0x7fffu + ((b.u >> 16) & 1u);
    return (ar >> 16) | (br & 0xffff0000u);
}
__device__ __forceinline__ v2f cvt2h(unsigned int u) {
    __half2 h = *(__half2*)&u;
    float2 f = __half22float2(h);
    v2f r; r[0] = f.x; r[1] = f.y; return r;
}

// MALL-coherent poll: 4 x dwordx4, 1 KB lane-stride apart, single drain.
// BYTE-IDENTICAL record protocol to the 18.16ms round-4 kernel.
__device__ __forceinline__ void poll4(const void* p, v4u& a, v4u& b, v4u& c, v4u& d) {
    asm volatile("global_load_dwordx4 %0, %4, off sc0 sc1\n\t"
                 "global_load_dwordx4 %1, %4, off offset:1024 sc0 sc1\n\t"
                 "global_load_dwordx4 %2, %4, off offset:2048 sc0 sc1\n\t"
                 "global_load_dwordx4 %3, %4, off offset:3072 sc0 sc1\n\t"
                 "s_waitcnt vmcnt(0)"
                 : "=&v"(a), "=&v"(b), "=&v"(c), "=&v"(d) : "v"(p) : "memory");
}
// Single 16B coherent store: h[8] as f16 + embedded toggle bit (one packet).
// RULE (round-5 lesson): publish grain is ONE 16B line-packet per WG — never
// fragment it (per-element 4B coherent stores caused MALL congestion collapse:
// FETCH 471MB->39GB, dur 18->100ms).
__device__ __forceinline__ void store16_coh(void* p, v4u v) {
    asm volatile("global_store_dwordx4 %0, %1, off sc0 sc1"
                 :: "v"(p), "v"(v) : "memory");
}

// 6-stage DPP wave64 sum; total lands in lane 63 (proven in round 4).
#define DPP_ADD(v, ctrl)                                                      \
    v += __int_as_float(__builtin_amdgcn_update_dpp(                          \
        0, __float_as_int(v), (ctrl), 0xf, 0xf, true))
#define RED_STAGE(ctrl) do { DPP_ADD(pr, ctrl); DPP_ADD(pz, ctrl);            \
                             DPP_ADD(pxn, ctrl); DPP_ADD(phn, ctrl); } while (0)

// Persistent GRU. 256 WGs x 576 threads: waves 0-7 compute (round-4 verbatim
// math), wave 8 polls/broadcasts/publishes. Global protocol byte-identical to
// round 4: 2 slots x 256 x 16B records, toggle(s)=((s>>1)^s)&1 in LSB of p.x.
//
// Per-step chain:
//   poller: poll4 slot(t&1) for toggle(t) -> broadcast hlds -> sync1 ->
//           lane0 spins on 8 tagged hpubd dwords (tag t+1 in high 16 bits,
//           f16 payload in low 16 — tag+payload atomic in ONE dword, so a
//           stale read self-detects) -> pack 16B packet -> coherent store.
//   compute: sync1 -> h-proj (4x ds_read_b128) -> DPP reduce -> act ->
//            lane63 writes tagged hpubd dword -> x-proj(t+1) (hidden under
//            the wire wait; cannot gate poll start — poller never loads x).
// No sync2. hlds overwrite safety is transitive: broadcast(t+1) <- detect(t+1)
// <- own store(t+1) <- all 8 tags(t+1) <- DPP reduce <- all lanes' step-t
// LDS reads (cross-lane data dependence orders them).
__global__ __launch_bounds__(kTHR)
void gru_persistent(const float* __restrict__ x,    // [S,H] f32
                    const float* __restrict__ Wih,  // [3H,H] f32
                    const float* __restrict__ Whh,  // [3H,H] f32
                    const float* __restrict__ bih,  // [3H] f32
                    const float* __restrict__ bhh,  // [3H] f32
                    float* __restrict__ out,        // [H] f32
                    unsigned char* __restrict__ rec) // 2 slots * 4096 B (zeroed)
{
    __shared__ __align__(16) unsigned short hlds[kH];  // h_t as f16, col c at [c]
    __shared__ __align__(16) unsigned int   hpubd[8];  // f16 | ((t+1)<<16)

    const int wg  = blockIdx.x;
    const int tid = threadIdx.x;
    const int wv  = tid >> 6;      // 0..8
    const int l   = tid & 63;      // 0..63

    if (tid < 8) hpubd[tid] = 0u;  // tags start at 1; 0 never false-triggers
    __syncthreads();               // executed once by ALL waves (incl. poller)

    if (wv == 8) {
        // ---------------- dedicated poller wave ----------------
        const char* base0 = (const char*)rec + l * 16;
#pragma unroll 1
        for (int t = 0; t < kS; ++t) {
            const unsigned int tg = (unsigned int)(((t >> 1) ^ t) & 1);
            const char* base = base0 + (t & 1) * 4096;
            v4u r0, r1, r2, r3;
            for (;;) {
                poll4(base, r0, r1, r2, r3);
                const int ok = ((r0.x & 1u) == tg) & ((r1.x & 1u) == tg) &
                               ((r2.x & 1u) == tg) & ((r3.x & 1u) == tg);
                if (__all(ok)) break;
            }
            // broadcast h_t to LDS: lane i writes records i, i+64, i+128, i+192
            *(v4u*)&hlds[l * 8]         = r0;
            *(v4u*)&hlds[(l + 64) * 8]  = r1;
            *(v4u*)&hlds[(l + 128) * 8] = r2;
            *(v4u*)&hlds[(l + 192) * 8] = r3;
            __syncthreads();   // sync1: release compute waves for step t

            // lane 0: spin on the 8 tagged dwords, pack, publish (t+1)
            if (l == 0) {
                const unsigned int tagx = ((unsigned int)(t + 1)) << 16;
                volatile unsigned int* hp = hpubd;
                unsigned int d0, d1, d2, d3, d4, d5, d6, d7;
                for (;;) {
                    d0 = hp[0]; d1 = hp[1]; d2 = hp[2]; d3 = hp[3];
                    d4 = hp[4]; d5 = hp[5]; d6 = hp[6]; d7 = hp[7];
                    const unsigned int mis =
                        (d0 ^ tagx) | (d1 ^ tagx) | (d2 ^ tagx) | (d3 ^ tagx) |
                        (d4 ^ tagx) | (d5 ^ tagx) | (d6 ^ tagx) | (d7 ^ tagx);
                    if ((mis & 0xffff0000u) == 0u) break;
                }
                v4u p;
                p.x = (d0 & 0xffffu) | (d1 << 16);
                p.y = (d2 & 0xffffu) | (d3 << 16);
                p.z = (d4 & 0xffffu) | (d5 << 16);
                p.w = (d6 & 0xffffu) | (d7 << 16);
                const unsigned int tgw =
                    (unsigned int)((((t + 1) >> 1) ^ (t + 1)) & 1);
                p.x = (p.x & ~1u) | tgw;
                store16_coh((char*)rec + ((t + 1) & 1) * 4096 + wg * 16, p);
            }
        }
        return;
    }

    // ---------------- compute waves (round-4 verbatim math) ----------------
    const int e  = wg * 8 + wv;
    const int cb = 4 * l;          // x-side col base
    const int hb = 8 * l;          // h-side col base

    v2f   whh2[3][4][4];
    uint2 wihp[3][8];
#pragma unroll
    for (int G = 0; G < 3; ++G) {
        const size_t row = (size_t)(G * kH + e) * kH;
#pragma unroll
        for (int m = 0; m < 4; ++m) {
            const size_t off = row + hb + 512 * m;
            const float4 w0 = *(const float4*)(Whh + off);
            const float4 w1 = *(const float4*)(Whh + off + 4);
            whh2[G][m][0][0] = w0.x; whh2[G][m][0][1] = w0.y;
            whh2[G][m][1][0] = w0.z; whh2[G][m][1][1] = w0.w;
            whh2[G][m][2][0] = w1.x; whh2[G][m][2][1] = w1.y;
            whh2[G][m][3][0] = w1.z; whh2[G][m][3][1] = w1.w;
        }
#pragma unroll
        for (int m = 0; m < 8; ++m) {
            const float4 iw = *(const float4*)(Wih + row + cb + 256 * m);
            wihp[G][m].x = pkbf(iw.x, iw.y);
            wihp[G][m].y = pkbf(iw.z, iw.w);
        }
    }
    const float bir  = bih[e];
    const float biz  = bih[kH + e];
    const float bin_ = bih[2 * kH + e];
    const float bhr  = bhh[e];
    const float bhz  = bhh[kH + e];
    const float bhn  = bhh[2 * kH + e];

    float hold = 0.0f;  // h for element e (valid on l==63)

    v2f zero2; zero2[0] = 0.f; zero2[1] = 0.f;
    v2f ar = zero2, az = zero2, an = zero2;
    {   // x-proj for step 0 (prologue)
#pragma unroll
        for (int m = 0; m < 8; ++m) {
            const float4 xv = *(const float4*)(x + cb + 256 * m);
            v2f x0; x0[0] = xv.x; x0[1] = xv.y;
            v2f x1; x1[0] = xv.z; x1[1] = xv.w;
            ar += unpk_bf(wihp[0][m].x) * x0 + unpk_bf(wihp[0][m].y) * x1;
            az += unpk_bf(wihp[1][m].x) * x0 + unpk_bf(wihp[1][m].y) * x1;
            an += unpk_bf(wihp[2][m].x) * x0 + unpk_bf(wihp[2][m].y) * x1;
        }
    }

#pragma unroll 1
    for (int t = 0; t < kS; ++t) {
        __syncthreads();   // sync1: poller has broadcast h_t into hlds

        // ---- h projection from LDS f16: 4x ds_read_b128 per lane ----
        v2f hr = zero2, hz = zero2, hn = zero2;
#pragma unroll
        for (int m = 0; m < 4; ++m) {
            const v4u hu = *(const v4u*)&hlds[hb + 512 * m];
            const v2f h0 = cvt2h(hu.x);
            const v2f h1 = cvt2h(hu.y);
            const v2f h2 = cvt2h(hu.z);
            const v2f h3 = cvt2h(hu.w);
            hr += whh2[0][m][0] * h0 + whh2[0][m][1] * h1 +
                  whh2[0][m][2] * h2 + whh2[0][m][3] * h3;
            hz += whh2[1][m][0] * h0 + whh2[1][m][1] * h1 +
                  whh2[1][m][2] * h2 + whh2[1][m][3] * h3;
            hn += whh2[2][m][0] * h0 + whh2[2][m][1] * h1 +
                  whh2[2][m][2] * h2 + whh2[2][m][3] * h3;
        }

        // ---- full-wave DPP reduce; totals land in lane 63 ----
        float pr  = ar[0] + ar[1] + hr[0] + hr[1];
        float pz  = az[0] + az[1] + hz[0] + hz[1];
        float pxn = an[0] + an[1];
        float phn = hn[0] + hn[1];
        RED_STAGE(0xB1);   // quad_perm xor1
        RED_STAGE(0x4E);   // quad_perm xor2
        RED_STAGE(0x141);  // row_half_mirror
        RED_STAGE(0x140);  // row_mirror
        RED_STAGE(0x142);  // row_bcast15
        RED_STAGE(0x143);  // row_bcast31

        if (l == 63) {
            const float r = 1.f / (1.f + __expf(-(pr + bir + bhr)));
            const float z = 1.f / (1.f + __expf(-(pz + biz + bhz)));
            const float a = (pxn + bin_) + r * (phn + bhn);
            const float ee = __expf(-2.f * fabsf(a));
            float th = (1.f - ee) / (1.f + ee);
            th = (a < 0.f) ? -th : th;
            hold = (1.f - z) * th + z * hold;
            const __half hh = __float2half(hold);
            const unsigned int hs = *(const unsigned short*)&hh;
            // tag + payload in ONE dword -> poller-visible atomically.
            *(volatile unsigned int*)&hpubd[wv] =
                hs | (((unsigned int)(t + 1)) << 16);
        }

        // ---- x projection for step t+1 (hidden under the wire wait; cannot
        //      gate poll start — the poller wave never touches x) ----
        {
            const float* xrow = x + (size_t)(t + 1 < kS ? t + 1 : t) * kH;
            ar = zero2; az = zero2; an = zero2;
#pragma unroll
            for (int m = 0; m < 8; ++m) {
                const float4 xv = *(const float4*)(xrow + cb + 256 * m);
                v2f x0; x0[0] = xv.x; x0[1] = xv.y;
                v2f x1; x1[0] = xv.z; x1[1] = xv.w;
                ar += unpk_bf(wihp[0][m].x) * x0 + unpk_bf(wihp[0][m].y) * x1;
                az += unpk_bf(wihp[1][m].x) * x0 + unpk_bf(wihp[1][m].y) * x1;
                an += unpk_bf(wihp[2][m].x) * x0 + unpk_bf(wihp[2][m].y) * x1;
            }
        }
    }

    if (l == 63)
        out[e] = hold;
}

extern "C" void kernel_launch(void* const* d_in, const int* in_sizes, int n_in,
                              void* d_out, int out_size, void* d_ws, size_t ws_size,
                              hipStream_t stream) {
    (void)in_sizes; (void)n_in; (void)out_size; (void)ws_size;
    const float* x   = (const float*)d_in[0];
    const float* Wih = (const float*)d_in[1];
    const float* Whh = (const float*)d_in[2];
    const float* bih = (const float*)d_in[3];
    const float* bhh = (const float*)d_in[4];

    unsigned char* rec = (unsigned char*)d_ws;   // 2 slots * 4096 B
    hipMemsetAsync(rec, 0, 8192, stream);        // h_0 = 0, slot-0 toggle 0; slot-1 waits
    gru_persistent<<<dim3(kNWG), dim3(kTHR), 0, stream>>>(
        x, Wih, Whh, bih, bhh, (float*)d_out, rec);
}

// Round 7
// 18345.599 us; speedup vs baseline: 5.4400x; 3.9359x over previous
//
#include <hip/hip_runtime.h>
#include <hip/hip_fp16.h>

static constexpr int kH   = 2048;
static constexpr int kS   = 8192;
static constexpr int kNWG = 256;
static constexpr int kTHR = 512;

typedef float        v2f __attribute__((ext_vector_type(2)));
typedef unsigned int v4u __attribute__((ext_vector_type(4)));

__device__ __forceinline__ v2f unpk_bf(unsigned int u) {
    union { unsigned int i; float f; } lo, hi;
    lo.i = u << 16; hi.i = u & 0xffff0000u;
    v2f r; r[0] = lo.f; r[1] = hi.f; return r;
}
__device__ __forceinline__ unsigned int pkbf(float lo, float hi) {
    union { float f; unsigned int u; } a, b; a.f = lo; b.f = hi;
    unsigned int ar = a.u + 0x7fffu + ((a.u >> 16) & 1u);
    unsigned int br = b.u + 0x7fffu + ((b.u >> 16) & 1u);
    return (ar >> 16) | (br & 0xffff0000u);
}
__device__ __forceinline__ v2f cvt2h(unsigned int u) {
    __half2 h = *(__half2*)&u;
    float2 f = __half22float2(h);
    v2f r; r[0] = f.x; r[1] = f.y; return r;
}

// Device-scope (sc1) coherent poll: 4 x dwordx4, 1 KB lane-stride, one drain.
// ROUND-7 A/B: was "sc0 sc1" (system scope). Cross-XCD coherence needs only
// device scope; system scope forces HBM-level write-through/ordering (r4's
// WRITE_SIZE was 2x the actual publish payload). Choreography is otherwise
// BYTE-IDENTICAL to the 18.16ms round-4 kernel.
// RULES (r1/r5/r6 lessons): wave 0 both polls and computes; polling bursts
// only in the post-publish window; publish grain is ONE 16B packet per WG.
__device__ __forceinline__ void poll4(const void* p, v4u& a, v4u& b, v4u& c, v4u& d) {
    asm volatile("global_load_dwordx4 %0, %4, off sc1\n\t"
                 "global_load_dwordx4 %1, %4, off offset:1024 sc1\n\t"
                 "global_load_dwordx4 %2, %4, off offset:2048 sc1\n\t"
                 "global_load_dwordx4 %3, %4, off offset:3072 sc1\n\t"
                 "s_waitcnt vmcnt(0)"
                 : "=&v"(a), "=&v"(b), "=&v"(c), "=&v"(d) : "v"(p) : "memory");
}
// Single 16B device-scope store: h[8] as f16 + embedded toggle (one packet).
__device__ __forceinline__ void store16_coh(void* p, v4u v) {
    asm volatile("global_store_dwordx4 %0, %1, off sc1"
                 :: "v"(p), "v"(v) : "memory");
}

// 6-stage DPP wave64 sum; total lands in lane 63 (proven in round 4).
#define DPP_ADD(v, ctrl)                                                      \
    v += __int_as_float(__builtin_amdgcn_update_dpp(                          \
        0, __float_as_int(v), (ctrl), 0xf, 0xf, true))
#define RED_STAGE(ctrl) do { DPP_ADD(pr, ctrl); DPP_ADD(pz, ctrl);            \
                             DPP_ADD(pxn, ctrl); DPP_ADD(phn, ctrl); } while (0)

// Persistent GRU. 256 WGs x 512 threads (8 waves), one WG per CU.
// Wave wv owns element e = wg*8+wv.
//   x-side:  lane l covers cols 4l + 256m (m<8)
//   h-side:  lane l covers cols 8l + 512m (m<4)  [b128-friendly]
// Publish protocol: WG's h[8] as f16 = ONE dwordx4 record; toggle(s) =
// ((s>>1)^s)&1 in record LSB; 2 slots (s&1) kill ABA. Wave 0 polls,
// __syncthreads releases, tid0 publishes after sync2.  (= round 4)
__global__ __launch_bounds__(kTHR, 2)
void gru_persistent(const float* __restrict__ x,    // [S,H] f32
                    const float* __restrict__ Wih,  // [3H,H] f32
                    const float* __restrict__ Whh,  // [3H,H] f32
                    const float* __restrict__ bih,  // [3H] f32
                    const float* __restrict__ bhh,  // [3H] f32
                    float* __restrict__ out,        // [H] f32
                    unsigned char* __restrict__ rec) // 2 slots * 4096 B (zeroed)
{
    __shared__ __align__(16) unsigned short hlds[kH];  // h_t as f16, col c at [c]
    __shared__ __align__(16) unsigned short hpub[8];

    const int wg  = blockIdx.x;
    const int tid = threadIdx.x;
    const int wv  = tid >> 6;      // 0..7
    const int l   = tid & 63;      // 0..63
    const int e   = wg * 8 + wv;
    const int cb  = 4 * l;         // x-side col base
    const int hb  = 8 * l;         // h-side col base

    // Weights: W_hh slice as f32 pairs (96 regs, 8-col blocks),
    //          W_ih as packed bf16 (24 regs, 4-col blocks).
    v2f   whh2[3][4][4];
    uint2 wihp[3][8];
#pragma unroll
    for (int G = 0; G < 3; ++G) {
        const size_t row = (size_t)(G * kH + e) * kH;
#pragma unroll
        for (int m = 0; m < 4; ++m) {
            const size_t off = row + hb + 512 * m;
            const float4 w0 = *(const float4*)(Whh + off);
            const float4 w1 = *(const float4*)(Whh + off + 4);
            whh2[G][m][0][0] = w0.x; whh2[G][m][0][1] = w0.y;
            whh2[G][m][1][0] = w0.z; whh2[G][m][1][1] = w0.w;
            whh2[G][m][2][0] = w1.x; whh2[G][m][2][1] = w1.y;
            whh2[G][m][3][0] = w1.z; whh2[G][m][3][1] = w1.w;
        }
#pragma unroll
        for (int m = 0; m < 8; ++m) {
            const float4 iw = *(const float4*)(Wih + row + cb + 256 * m);
            wihp[G][m].x = pkbf(iw.x, iw.y);
            wihp[G][m].y = pkbf(iw.z, iw.w);
        }
    }
    const float bir  = bih[e];
    const float biz  = bih[kH + e];
    const float bin_ = bih[2 * kH + e];
    const float bhr  = bhh[e];
    const float bhz  = bhh[kH + e];
    const float bhn  = bhh[2 * kH + e];

    float hold = 0.0f;  // h for element e (valid on l==63)

#pragma unroll 1
    for (int t = 0; t < kS; ++t) {
        // ---- x projection (cached loads; overlaps inter-WG skew) ----
        const float* xrow = x + (size_t)t * kH;
        v2f ar = {0.f, 0.f}, az = {0.f, 0.f}, an = {0.f, 0.f};
#pragma unroll
        for (int m = 0; m < 8; ++m) {
            const float4 xv = *(const float4*)(xrow + cb + 256 * m);
            v2f x0; x0[0] = xv.x; x0[1] = xv.y;
            v2f x1; x1[0] = xv.z; x1[1] = xv.w;
            ar += unpk_bf(wihp[0][m].x) * x0 + unpk_bf(wihp[0][m].y) * x1;
            az += unpk_bf(wihp[1][m].x) * x0 + unpk_bf(wihp[1][m].y) * x1;
            an += unpk_bf(wihp[2][m].x) * x0 + unpk_bf(wihp[2][m].y) * x1;
        }

        // ---- wave 0: poll all 256 records for step-t toggle; data = payload ----
        if (tid < 64) {
            const unsigned int tg = (unsigned int)(((t >> 1) ^ t) & 1);
            const char* base = (const char*)rec + (t & 1) * 4096 + tid * 16;
            v4u r0, r1, r2, r3;
            for (;;) {
                poll4(base, r0, r1, r2, r3);
                const int ok = ((r0.x & 1u) == tg) & ((r1.x & 1u) == tg) &
                               ((r2.x & 1u) == tg) & ((r3.x & 1u) == tg);
                if (__all(ok)) break;
            }
            // broadcast h_t to LDS: lane i writes records i, i+64, i+128, i+192
            *(v4u*)&hlds[tid * 8]         = r0;
            *(v4u*)&hlds[(tid + 64) * 8]  = r1;
            *(v4u*)&hlds[(tid + 128) * 8] = r2;
            *(v4u*)&hlds[(tid + 192) * 8] = r3;
        }
        __syncthreads();   // sync1: orders hlds broadcast vs h-proj reads

        // ---- h projection from LDS f16: 4x ds_read_b128 per lane ----
        v2f hr = {0.f, 0.f}, hz = {0.f, 0.f}, hn = {0.f, 0.f};
#pragma unroll
        for (int m = 0; m < 4; ++m) {
            const v4u hu = *(const v4u*)&hlds[hb + 512 * m];
            const v2f h0 = cvt2h(hu.x);
            const v2f h1 = cvt2h(hu.y);
            const v2f h2 = cvt2h(hu.z);
            const v2f h3 = cvt2h(hu.w);
            hr += whh2[0][m][0] * h0 + whh2[0][m][1] * h1 +
                  whh2[0][m][2] * h2 + whh2[0][m][3] * h3;
            hz += whh2[1][m][0] * h0 + whh2[1][m][1] * h1 +
                  whh2[1][m][2] * h2 + whh2[1][m][3] * h3;
            hn += whh2[2][m][0] * h0 + whh2[2][m][1] * h1 +
                  whh2[2][m][2] * h2 + whh2[2][m][3] * h3;
        }

        // ---- full-wave DPP reduce (VALU pipe); sum lands in lane 63 ----
        float pr  = ar[0] + ar[1] + hr[0] + hr[1];
        float pz  = az[0] + az[1] + hz[0] + hz[1];
        float pxn = an[0] + an[1];
        float phn = hn[0] + hn[1];
        RED_STAGE(0xB1);   // quad_perm xor1
        RED_STAGE(0x4E);   // quad_perm xor2
        RED_STAGE(0x141);  // row_half_mirror
        RED_STAGE(0x140);  // row_mirror
        RED_STAGE(0x142);  // row_bcast15
        RED_STAGE(0x143);  // row_bcast31

        if (l == 63) {
            const float r = 1.f / (1.f + __expf(-(pr + bir + bhr)));
            const float z = 1.f / (1.f + __expf(-(pz + biz + bhz)));
            const float a = (pxn + bin_) + r * (phn + bhn);
            const float ee = __expf(-2.f * fabsf(a));
            float th = (1.f - ee) / (1.f + ee);
            th = (a < 0.f) ? -th : th;
            hold = (1.f - z) * th + z * hold;
            const __half hh = __float2half(hold);
            hpub[wv] = *(const unsigned short*)&hh;
        }
        __syncthreads();   // sync2: orders hpub writes vs tid0 pack+store

        // ---- publish: ONE 16B device-scope store (data + toggle, one packet) ----
        if (tid == 0) {
            v4u p = *(const v4u*)hpub;
            const unsigned int tgw = (unsigned int)((((t + 1) >> 1) ^ (t + 1)) & 1);
            p.x = (p.x & ~1u) | tgw;
            store16_coh((char*)rec + ((t + 1) & 1) * 4096 + wg * 16, p);
        }
    }

    if (l == 63)
        out[e] = hold;
}

extern "C" void kernel_launch(void* const* d_in, const int* in_sizes, int n_in,
                              void* d_out, int out_size, void* d_ws, size_t ws_size,
                              hipStream_t stream) {
    (void)in_sizes; (void)n_in; (void)out_size; (void)ws_size;
    const float* x   = (const float*)d_in[0];
    const float* Wih = (const float*)d_in[1];
    const float* Whh = (const float*)d_in[2];
    const float* bih = (const float*)d_in[3];
    const float* bhh = (const float*)d_in[4];

    unsigned char* rec = (unsigned char*)d_ws;   // 2 slots * 4096 B
    hipMemsetAsync(rec, 0, 8192, stream);        // h_0 = 0, slot-0 toggle 0; slot-1 waits
    gru_persistent<<<dim3(kNWG), dim3(kTHR), 0, stream>>>(
        x, Wih, Whh, bih, bhh, (float*)d_out, rec);
}